// Round 4
// baseline (1359.020 us; speedup 1.0000x reference)
//
#include <hip/hip_runtime.h>
#include <cstddef>

// ---------------- conv1 v3 (unchanged): (32,3,152,152) -> relu 11x11 -> (32,32,142,142)
__global__ __launch_bounds__(256, 2) void conv1_v3(const float* __restrict__ x,
                                                   const float* __restrict__ w,
                                                   const float* __restrict__ bias,
                                                   float* __restrict__ out) {
  __shared__ __align__(16) float wsp[33 * 32 * 12];
  __shared__ __align__(16) float xs[3][26][44];
  const int wt = blockIdx.x, ht = blockIdx.y, b = blockIdx.z;
  const int tid = threadIdx.x;
  const int posg = tid & 31;
  const int ocg = tid >> 5;
  const int owg = posg & 1;
  const int ohl = posg >> 1;
  const int ih0 = ht * 16, iw0 = wt * 32;

  for (int j = tid; j < 11616; j += 256) {
    const int kw = j % 11, oc = (j / 11) % 32, r = j / 352;
    wsp[(r * 32 + oc) * 12 + kw] = w[oc * 363 + r * 11 + kw];
  }
  for (int j = tid; j < 3 * 26 * 42; j += 256) {
    const int ic = j / 1092, r = (j % 1092) / 42, c = j % 42;
    const int ih = min(ih0 + r, 151), iw = min(iw0 + c, 151);
    xs[ic][r][c] = x[((size_t)b * 3 + ic) * 23104 + ih * 152 + iw];
  }
  __syncthreads();

  const int oh = ih0 + ohl;
  if (oh >= 142) return;
  float acc[4][16] = {};
  for (int ic = 0; ic < 3; ++ic) {
    for (int kh = 0; kh < 11; ++kh) {
      const int r = ic * 11 + kh;
      float xv[28];
      const float* xr = &xs[ic][ohl + kh][owg * 16];
      #pragma unroll
      for (int j = 0; j < 7; ++j) *(float4*)&xv[4 * j] = *(const float4*)&xr[4 * j];
      float wv[4][12];
      #pragma unroll
      for (int o = 0; o < 4; ++o) {
        const float* wr = &wsp[(r * 32 + ocg * 4 + o) * 12];
        *(float4*)&wv[o][0] = *(const float4*)&wr[0];
        *(float4*)&wv[o][4] = *(const float4*)&wr[4];
        *(float4*)&wv[o][8] = *(const float4*)&wr[8];
      }
      #pragma unroll
      for (int kw = 0; kw < 11; ++kw)
        #pragma unroll
        for (int o = 0; o < 4; ++o)
          #pragma unroll
          for (int p = 0; p < 16; ++p)
            acc[o][p] += xv[kw + p] * wv[o][kw];
    }
  }

  const int ow0 = iw0 + owg * 16;
  #pragma unroll
  for (int o = 0; o < 4; ++o) {
    const int oc = ocg * 4 + o;
    const float bv = bias[oc];
    float* op = &out[(((size_t)b * 32 + oc) * 142 + oh) * 142 + ow0];
    if (ow0 + 16 <= 142) {
      #pragma unroll
      for (int p = 0; p < 16; p += 2) {
        float2 rv;
        rv.x = fmaxf(acc[o][p] + bv, 0.f);
        rv.y = fmaxf(acc[o][p + 1] + bv, 0.f);
        *(float2*)&op[p] = rv;
      }
    } else {
      for (int p = 0; p < 16; ++p)
        if (ow0 + p < 142) op[p] = fmaxf(acc[o][p] + bv, 0.f);
    }
  }
}

// ---------------- maxpool 3x3 s2 p1 (unchanged)
__global__ __launch_bounds__(256) void pool_3_2_1(const float* __restrict__ in,
                                                  float* __restrict__ out) {
  const int idx = blockIdx.x * 256 + threadIdx.x;
  const int total = 32 * 32 * 71 * 71;
  if (idx >= total) return;
  const int ow = idx % 71;
  const int oh = (idx / 71) % 71;
  const int bc = idx / (71 * 71);
  const float* base = in + (size_t)bc * 142 * 142;
  float m = -1e30f;
  #pragma unroll
  for (int kh = 0; kh < 3; ++kh) {
    const int ih = oh * 2 - 1 + kh;
    if (ih < 0 || ih >= 142) continue;
    #pragma unroll
    for (int kw = 0; kw < 3; ++kw) {
      const int iw = ow * 2 - 1 + kw;
      if (iw < 0 || iw >= 142) continue;
      m = fmaxf(m, base[ih * 142 + iw]);
    }
  }
  out[idx] = m;
}

// ---------------- conv2 (unchanged): ic-split x4 partials + combine
__global__ __launch_bounds__(128, 2) void conv2_part(const float* __restrict__ x,
                                                     const float* __restrict__ w,
                                                     float* __restrict__ part) {
  __shared__ __align__(16) float wsp[2 * 9 * 16 * 12];
  __shared__ __align__(16) float xs[2][24][44];
  const int wt = blockIdx.x, ht = blockIdx.y;
  const int b = blockIdx.z >> 2, icg = blockIdx.z & 3;
  const int tid = threadIdx.x;
  const int posg = tid & 31;
  const int ocg = tid >> 5;
  const int owg = posg & 1, ohl = posg >> 1;
  const int ih0 = ht * 16, iw0 = wt * 32;
  float acc[4][16] = {};

  for (int ch = 0; ch < 4; ++ch) {
    __syncthreads();
    for (int j = tid; j < 2 * 9 * 16 * 9; j += 128) {
      const int kw = j % 9, oc = (j / 9) % 16, kh = (j / 144) % 9, icl = j / 1296;
      wsp[((icl * 9 + kh) * 16 + oc) * 12 + kw] =
          w[(size_t)oc * 2592 + (icg * 8 + ch * 2 + icl) * 81 + kh * 9 + kw];
    }
    for (int j = tid; j < 2 * 24 * 40; j += 128) {
      const int icl = j / 960, r = (j % 960) / 40, c = j % 40;
      const int ih = min(ih0 + r, 70), iw = min(iw0 + c, 70);
      xs[icl][r][c] =
          x[((size_t)b * 32 + icg * 8 + ch * 2 + icl) * 5041 + ih * 71 + iw];
    }
    __syncthreads();
    for (int icl = 0; icl < 2; ++icl) {
      for (int kh = 0; kh < 9; ++kh) {
        float xv[24];
        const float* xr = &xs[icl][ohl + kh][owg * 16];
        #pragma unroll
        for (int j = 0; j < 6; ++j) *(float4*)&xv[4 * j] = *(const float4*)&xr[4 * j];
        float wv[4][9];
        #pragma unroll
        for (int o = 0; o < 4; ++o) {
          const float* wr = &wsp[((icl * 9 + kh) * 16 + ocg * 4 + o) * 12];
          *(float4*)&wv[o][0] = *(const float4*)&wr[0];
          *(float4*)&wv[o][4] = *(const float4*)&wr[4];
          wv[o][8] = wr[8];
        }
        #pragma unroll
        for (int kw = 0; kw < 9; ++kw)
          #pragma unroll
          for (int o = 0; o < 4; ++o)
            #pragma unroll
            for (int p = 0; p < 16; ++p)
              acc[o][p] += xv[kw + p] * wv[o][kw];
      }
    }
  }

  const int oh = ih0 + ohl;
  if (oh >= 63) return;
  const int ow0 = iw0 + owg * 16;
  float* pp = part + (size_t)icg * 2032128;
  #pragma unroll
  for (int o = 0; o < 4; ++o) {
    const int oc = ocg * 4 + o;
    float* op = &pp[(((size_t)b * 16 + oc) * 63 + oh) * 63 + ow0];
    #pragma unroll
    for (int p = 0; p < 16; ++p)
      if (ow0 + p < 63) op[p] = acc[o][p];
  }
}

__global__ __launch_bounds__(256) void conv2_combine(const float* __restrict__ part,
                                                     const float* __restrict__ bias,
                                                     float* __restrict__ out) {
  const int i = blockIdx.x * 256 + threadIdx.x;
  if (i >= 2032128) return;
  const int oc = (i / 3969) & 15;
  const float v = part[i] + part[i + 2032128] + part[i + 2 * 2032128] +
                  part[i + 3 * 2032128] + bias[oc];
  out[i] = fmaxf(v, 0.f);
}

// ---------------- local conv v4: 1 wave = 2 positions; thread = 4 oc x 4 b.
// x staged per-ic in LDS, XOR-swizzled (16B group ^= b>>2) -> conflict-free
// b128 reads AND writes. w read direct from global (float4 per 4k, 8-way lane
// dedup, streamed once). KHW % 4 == 1 for all layers: main 4k loop + 1 tail.
template <int KH, int S, int IH, int OH>
__global__ __launch_bounds__(64) void lc_v4(const float* __restrict__ x,
                                            const float* __restrict__ w,
                                            const float* __restrict__ bias,
                                            float* __restrict__ out) {
  constexpr int KHW = KH * KH;
  constexpr int NPOS = OH * OH;
  constexpr int NCH = KHW * 16;                       // per-oc weight stride
  constexpr int GROUPS = ((((KHW - 1) >> 2) | 7) + 1); // 16B groups per row
  constexpr int ROWW = GROUPS * 4;                    // words per b-row
  __shared__ __align__(16) float xs[2 * 32 * ROWW];

  const int pos0 = blockIdx.x * 2;
  const int lane = threadIdx.x;
  const int p = lane >> 5, t = lane & 31;
  const int og = t & 3, bg = t >> 2;                  // oc0 = og*4, b0 = bg*4
  const int mypos = min(pos0 + p, NPOS - 1);
  const int oh = mypos / OH, ow = mypos % OH;
  const float* wbase = w + (size_t)mypos * 16 * NCH + (size_t)(og * 4) * NCH;
  float* const xp = &xs[p * (32 * ROWW)];

  float acc[4][4] = {};
  for (int ic = 0; ic < 16; ++ic) {
    __syncthreads();
    for (int j = lane; j < 2 * 32 * KHW; j += 64) {
      const int pj = j / (32 * KHW);
      const int r = j % (32 * KHW);
      const int b = r / KHW, k = r % KHW;
      const int posj = min(pos0 + pj, NPOS - 1);
      const int ohj = posj / OH, owj = posj % OH;
      const int kh = k / KH, kw = k % KH;
      const float v =
          x[(((size_t)b * 16 + ic) * IH + ohj * S + kh) * IH + owj * S + kw];
      xs[pj * (32 * ROWW) + b * ROWW +
         ((((k >> 2) ^ ((b >> 2) & 7)) << 2) | (k & 3))] = v;
    }
    __syncthreads();
    const float* wic = wbase + ic * KHW;
    #pragma unroll 2
    for (int kc = 0; kc < KHW / 4; ++kc) {
      const int k = kc * 4;
      float4 wf[4];
      #pragma unroll
      for (int o = 0; o < 4; ++o)
        wf[o] = *(const float4*)&wic[o * NCH + k];
      float4 xv[4];
      #pragma unroll
      for (int i = 0; i < 4; ++i)
        xv[i] = *(const float4*)&xp[(bg * 4 + i) * ROWW + ((kc ^ bg) << 2)];
      #pragma unroll
      for (int o = 0; o < 4; ++o)
        #pragma unroll
        for (int i = 0; i < 4; ++i) {
          acc[o][i] += wf[o].x * xv[i].x;
          acc[o][i] += wf[o].y * xv[i].y;
          acc[o][i] += wf[o].z * xv[i].z;
          acc[o][i] += wf[o].w * xv[i].w;
        }
    }
    {  // tail k = KHW-1
      const int k = KHW - 1;
      float wt[4];
      #pragma unroll
      for (int o = 0; o < 4; ++o) wt[o] = wic[o * NCH + k];
      #pragma unroll
      for (int i = 0; i < 4; ++i) {
        const float xt = xp[(bg * 4 + i) * ROWW +
                            ((((k >> 2) ^ bg) << 2) | (k & 3))];
        #pragma unroll
        for (int o = 0; o < 4; ++o) acc[o][i] += wt[o] * xt;
      }
    }
  }

  if (pos0 + p < NPOS) {
    #pragma unroll
    for (int o = 0; o < 4; ++o) {
      const int oc = og * 4 + o;
      const float bv = bias[oc * NPOS + mypos];
      #pragma unroll
      for (int i = 0; i < 4; ++i) {
        const int b = bg * 4 + i;
        out[(((size_t)b * 16 + oc) * OH + oh) * OH + ow] =
            fmaxf(acc[o][i] + bv, 0.f);
      }
    }
  }
}

// ---------------- fc1 (unchanged): transpose + reg-tiled GEMM
__global__ __launch_bounds__(256) void transpose_x(const float* __restrict__ h,
                                                   float* __restrict__ xt) {
  __shared__ float t[32][33];
  const int k0 = blockIdx.x * 32;
  const int lk = threadIdx.x & 31, lb = threadIdx.x >> 5;
  for (int bb = lb; bb < 32; bb += 8) {
    const int k = k0 + lk;
    t[bb][lk] = (k < 7056) ? h[(size_t)bb * 7056 + k] : 0.f;
  }
  __syncthreads();
  for (int kk = lb; kk < 32; kk += 8) {
    const int k = k0 + kk;
    if (k < 7056) xt[(size_t)k * 32 + lk] = t[lk][kk];
  }
}

__global__ __launch_bounds__(256) void fc1_v2(const float* __restrict__ xt,
                                              const float* __restrict__ w,
                                              const float* __restrict__ bias,
                                              float* __restrict__ out) {
  const int lane = threadIdx.x & 63;
  const int b0 = (threadIdx.x >> 6) * 8;
  const int n0 = blockIdx.x * 8;
  float acc[8][8] = {};
  for (int it = 0; it < 28; ++it) {
    const int kb = it * 256 + lane * 4;
    float4 wf[8], xa[4], xb[4];
    if (kb < 7056) {
      #pragma unroll
      for (int n = 0; n < 8; ++n)
        wf[n] = *(const float4*)&w[(size_t)(n0 + n) * 7056 + kb];
      #pragma unroll
      for (int j = 0; j < 4; ++j) {
        xa[j] = *(const float4*)&xt[(size_t)(kb + j) * 32 + b0];
        xb[j] = *(const float4*)&xt[(size_t)(kb + j) * 32 + b0 + 4];
      }
    } else {
      #pragma unroll
      for (int n = 0; n < 8; ++n) wf[n] = make_float4(0.f, 0.f, 0.f, 0.f);
      #pragma unroll
      for (int j = 0; j < 4; ++j) {
        xa[j] = make_float4(0.f, 0.f, 0.f, 0.f);
        xb[j] = make_float4(0.f, 0.f, 0.f, 0.f);
      }
    }
    #pragma unroll
    for (int n = 0; n < 8; ++n) {
      const float wk[4] = {wf[n].x, wf[n].y, wf[n].z, wf[n].w};
      #pragma unroll
      for (int j = 0; j < 4; ++j) {
        acc[n][0] += wk[j] * xa[j].x;
        acc[n][1] += wk[j] * xa[j].y;
        acc[n][2] += wk[j] * xa[j].z;
        acc[n][3] += wk[j] * xa[j].w;
        acc[n][4] += wk[j] * xb[j].x;
        acc[n][5] += wk[j] * xb[j].y;
        acc[n][6] += wk[j] * xb[j].z;
        acc[n][7] += wk[j] * xb[j].w;
      }
    }
  }
  #pragma unroll
  for (int n = 0; n < 8; ++n)
    #pragma unroll
    for (int c = 0; c < 8; ++c)
      #pragma unroll
      for (int m = 1; m < 64; m <<= 1)
        acc[n][c] += __shfl_xor(acc[n][c], m, 64);
  float val = 0.f;
  #pragma unroll
  for (int n = 0; n < 8; ++n)
    #pragma unroll
    for (int c = 0; c < 8; ++c)
      if (lane == n * 8 + c) val = acc[n][c];
  const int n_l = lane >> 3, b_l = lane & 7;
  out[(size_t)(b0 + b_l) * 4096 + n0 + n_l] = val + bias[n0 + n_l];
}

extern "C" void kernel_launch(void* const* d_in, const int* in_sizes, int n_in,
                              void* d_out, int out_size, void* d_ws, size_t ws_size,
                              hipStream_t stream) {
  const float* x       = (const float*)d_in[0];
  const float* conv1_w = (const float*)d_in[1];
  const float* conv1_b = (const float*)d_in[2];
  const float* conv2_w = (const float*)d_in[3];
  const float* conv2_b = (const float*)d_in[4];
  const float* lc1_w   = (const float*)d_in[5];
  const float* lc1_b   = (const float*)d_in[6];
  const float* lc2_w   = (const float*)d_in[7];
  const float* lc2_b   = (const float*)d_in[8];
  const float* lc3_w   = (const float*)d_in[9];
  const float* lc3_b   = (const float*)d_in[10];
  const float* fc1_w   = (const float*)d_in[11];
  const float* fc1_b   = (const float*)d_in[12];
  float* out = (float*)d_out;
  char* ws = (char*)d_ws;

  float* h1 = (float*)(ws + 0);            // 32*32*142*142      82,591,744 B
  float* p1 = (float*)(ws + 82591744);     // 32*32*71*71        20,647,936 B
  float* h2 = (float*)(ws + 103239680);    // 32*16*63*63         8,128,512 B
  float* h3 = (float*)(ws + 0);            // 32*16*55*55         6,195,200 B
  float* h4 = (float*)(ws + 8388608);      // 32*16*25*25         1,280,000 B
  float* h5 = (float*)(ws + 16777216);     // 32*16*21*21           903,168 B
  float* xt = (float*)(ws + 33554432);     // 7056*32               903,168 B
  float* c2p = (float*)(ws + 41943040);    // 4*32*16*63*63      32,514,048 B

  conv1_v3<<<dim3(5, 9, 32), 256, 0, stream>>>(x, conv1_w, conv1_b, h1);
  pool_3_2_1<<<20164, 256, 0, stream>>>(h1, p1);
  conv2_part<<<dim3(2, 4, 128), 128, 0, stream>>>(p1, conv2_w, c2p);
  conv2_combine<<<7938, 256, 0, stream>>>(c2p, conv2_b, h2);
  lc_v4<9, 1, 63, 55><<<(55 * 55 + 1) / 2, 64, 0, stream>>>(h2, lc1_w, lc1_b, h3);
  lc_v4<7, 2, 55, 25><<<(25 * 25 + 1) / 2, 64, 0, stream>>>(h3, lc2_w, lc2_b, h4);
  lc_v4<5, 1, 25, 21><<<(21 * 21 + 1) / 2, 64, 0, stream>>>(h4, lc3_w, lc3_b, h5);
  transpose_x<<<221, 256, 0, stream>>>(h5, xt);
  fc1_v2<<<512, 256, 0, stream>>>(xt, fc1_w, fc1_b, out);
}

// Round 5
// 960.870 us; speedup vs baseline: 1.4144x; 1.4144x over previous
//
#include <hip/hip_runtime.h>
#include <cstddef>

// ---------------- conv1 v3: (32,3,152,152) -> relu 11x11 -> (32,32,142,142)
__global__ __launch_bounds__(256, 2) void conv1_v3(const float* __restrict__ x,
                                                   const float* __restrict__ w,
                                                   const float* __restrict__ bias,
                                                   float* __restrict__ out) {
  __shared__ __align__(16) float wsp[33 * 32 * 12];
  __shared__ __align__(16) float xs[3][26][44];
  const int wt = blockIdx.x, ht = blockIdx.y, b = blockIdx.z;
  const int tid = threadIdx.x;
  const int posg = tid & 31;
  const int ocg = tid >> 5;
  const int owg = posg & 1;
  const int ohl = posg >> 1;
  const int ih0 = ht * 16, iw0 = wt * 32;

  for (int j = tid; j < 11616; j += 256) {
    const int kw = j % 11, oc = (j / 11) % 32, r = j / 352;
    wsp[(r * 32 + oc) * 12 + kw] = w[oc * 363 + r * 11 + kw];
  }
  for (int j = tid; j < 3 * 26 * 42; j += 256) {
    const int ic = j / 1092, r = (j % 1092) / 42, c = j % 42;
    const int ih = min(ih0 + r, 151), iw = min(iw0 + c, 151);
    xs[ic][r][c] = x[((size_t)b * 3 + ic) * 23104 + ih * 152 + iw];
  }
  __syncthreads();

  const int oh = ih0 + ohl;
  if (oh >= 142) return;
  float acc[4][16] = {};
  for (int ic = 0; ic < 3; ++ic) {
    for (int kh = 0; kh < 11; ++kh) {
      const int r = ic * 11 + kh;
      float xv[28];
      const float* xr = &xs[ic][ohl + kh][owg * 16];
      #pragma unroll
      for (int j = 0; j < 7; ++j) *(float4*)&xv[4 * j] = *(const float4*)&xr[4 * j];
      float wv[4][12];
      #pragma unroll
      for (int o = 0; o < 4; ++o) {
        const float* wr = &wsp[(r * 32 + ocg * 4 + o) * 12];
        *(float4*)&wv[o][0] = *(const float4*)&wr[0];
        *(float4*)&wv[o][4] = *(const float4*)&wr[4];
        *(float4*)&wv[o][8] = *(const float4*)&wr[8];
      }
      #pragma unroll
      for (int kw = 0; kw < 11; ++kw)
        #pragma unroll
        for (int o = 0; o < 4; ++o)
          #pragma unroll
          for (int p = 0; p < 16; ++p)
            acc[o][p] += xv[kw + p] * wv[o][kw];
    }
  }

  const int ow0 = iw0 + owg * 16;
  #pragma unroll
  for (int o = 0; o < 4; ++o) {
    const int oc = ocg * 4 + o;
    const float bv = bias[oc];
    float* op = &out[(((size_t)b * 32 + oc) * 142 + oh) * 142 + ow0];
    if (ow0 + 16 <= 142) {
      #pragma unroll
      for (int p = 0; p < 16; p += 2) {
        float2 rv;
        rv.x = fmaxf(acc[o][p] + bv, 0.f);
        rv.y = fmaxf(acc[o][p + 1] + bv, 0.f);
        *(float2*)&op[p] = rv;
      }
    } else {
      for (int p = 0; p < 16; ++p)
        if (ow0 + p < 142) op[p] = fmaxf(acc[o][p] + bv, 0.f);
    }
  }
}

// ---------------- maxpool 3x3 s2 p1
__global__ __launch_bounds__(256) void pool_3_2_1(const float* __restrict__ in,
                                                  float* __restrict__ out) {
  const int idx = blockIdx.x * 256 + threadIdx.x;
  const int total = 32 * 32 * 71 * 71;
  if (idx >= total) return;
  const int ow = idx % 71;
  const int oh = (idx / 71) % 71;
  const int bc = idx / (71 * 71);
  const float* base = in + (size_t)bc * 142 * 142;
  float m = -1e30f;
  #pragma unroll
  for (int kh = 0; kh < 3; ++kh) {
    const int ih = oh * 2 - 1 + kh;
    if (ih < 0 || ih >= 142) continue;
    #pragma unroll
    for (int kw = 0; kw < 3; ++kw) {
      const int iw = ow * 2 - 1 + kw;
      if (iw < 0 || iw >= 142) continue;
      m = fmaxf(m, base[ih * 142 + iw]);
    }
  }
  out[idx] = m;
}

// ---------------- conv2: ic-split x4 partials + combine
__global__ __launch_bounds__(128, 2) void conv2_part(const float* __restrict__ x,
                                                     const float* __restrict__ w,
                                                     float* __restrict__ part) {
  __shared__ __align__(16) float wsp[2 * 9 * 16 * 12];
  __shared__ __align__(16) float xs[2][24][44];
  const int wt = blockIdx.x, ht = blockIdx.y;
  const int b = blockIdx.z >> 2, icg = blockIdx.z & 3;
  const int tid = threadIdx.x;
  const int posg = tid & 31;
  const int ocg = tid >> 5;
  const int owg = posg & 1, ohl = posg >> 1;
  const int ih0 = ht * 16, iw0 = wt * 32;
  float acc[4][16] = {};

  for (int ch = 0; ch < 4; ++ch) {
    __syncthreads();
    for (int j = tid; j < 2 * 9 * 16 * 9; j += 128) {
      const int kw = j % 9, oc = (j / 9) % 16, kh = (j / 144) % 9, icl = j / 1296;
      wsp[((icl * 9 + kh) * 16 + oc) * 12 + kw] =
          w[(size_t)oc * 2592 + (icg * 8 + ch * 2 + icl) * 81 + kh * 9 + kw];
    }
    for (int j = tid; j < 2 * 24 * 40; j += 128) {
      const int icl = j / 960, r = (j % 960) / 40, c = j % 40;
      const int ih = min(ih0 + r, 70), iw = min(iw0 + c, 70);
      xs[icl][r][c] =
          x[((size_t)b * 32 + icg * 8 + ch * 2 + icl) * 5041 + ih * 71 + iw];
    }
    __syncthreads();
    for (int icl = 0; icl < 2; ++icl) {
      for (int kh = 0; kh < 9; ++kh) {
        float xv[24];
        const float* xr = &xs[icl][ohl + kh][owg * 16];
        #pragma unroll
        for (int j = 0; j < 6; ++j) *(float4*)&xv[4 * j] = *(const float4*)&xr[4 * j];
        float wv[4][9];
        #pragma unroll
        for (int o = 0; o < 4; ++o) {
          const float* wr = &wsp[((icl * 9 + kh) * 16 + ocg * 4 + o) * 12];
          *(float4*)&wv[o][0] = *(const float4*)&wr[0];
          *(float4*)&wv[o][4] = *(const float4*)&wr[4];
          wv[o][8] = wr[8];
        }
        #pragma unroll
        for (int kw = 0; kw < 9; ++kw)
          #pragma unroll
          for (int o = 0; o < 4; ++o)
            #pragma unroll
            for (int p = 0; p < 16; ++p)
              acc[o][p] += xv[kw + p] * wv[o][kw];
      }
    }
  }

  const int oh = ih0 + ohl;
  if (oh >= 63) return;
  const int ow0 = iw0 + owg * 16;
  float* pp = part + (size_t)icg * 2032128;
  #pragma unroll
  for (int o = 0; o < 4; ++o) {
    const int oc = ocg * 4 + o;
    float* op = &pp[(((size_t)b * 16 + oc) * 63 + oh) * 63 + ow0];
    #pragma unroll
    for (int p = 0; p < 16; ++p)
      if (ow0 + p < 63) op[p] = acc[o][p];
  }
}

__global__ __launch_bounds__(256) void conv2_combine(const float* __restrict__ part,
                                                     const float* __restrict__ bias,
                                                     float* __restrict__ out) {
  const int i = blockIdx.x * 256 + threadIdx.x;
  if (i >= 2032128) return;
  const int oc = (i / 3969) & 15;
  const float v = part[i] + part[i + 2032128] + part[i + 2 * 2032128] +
                  part[i + 3 * 2032128] + bias[oc];
  out[i] = fmaxf(v, 0.f);
}

// ---------------- local conv v5: block = 4 waves = 8 consecutive positions in
// one output row (shared x patch staged once per ic); ic-split x4 across
// blockIdx.y into f32 partials. Wave = 2 pos x (4 og x 8 bg); thread = 4oc x 4b.
// Weights read direct from global (float4 over k, 8-way lane dedup, streamed
// once since ic-slices are disjoint). x patch [KH][COLS][b pad 36] -> aligned
// conflict-free ds_read_b128 over b.
template <int KH, int S, int IH, int OH>
__global__ __launch_bounds__(256) void lc_v5(const float* __restrict__ x,
                                             const float* __restrict__ w,
                                             float* __restrict__ part) {
  constexpr int KHW = KH * KH;
  constexpr int NPOS = OH * OH;
  constexpr int TILE = 8;
  constexpr int COLS = S * (TILE - 1) + KH;
  constexpr int TPR = (OH + TILE - 1) / TILE;
  constexpr int BSTR = 36;
  __shared__ __align__(16) float xs[KH * COLS * BSTR];

  const int tile = blockIdx.x % TPR;
  const int oh = blockIdx.x / TPR;
  const int icg = blockIdx.y;
  const int ow0 = min(tile * TILE, OH - TILE);
  const int tid = threadIdx.x;
  const int lane = tid & 63, wv = tid >> 6;
  const int p = lane >> 5, t = lane & 31;
  const int og = t & 3, bg = t >> 2;
  const int ow_off = wv * 2 + p;
  const int myow = ow0 + ow_off;
  const int pos = oh * OH + myow;
  const float* wbase =
      w + ((size_t)pos * 16 + og * 4) * (16 * KHW) + (size_t)(icg * 4) * KHW;
  const int in_row0 = oh * S, in_col0 = ow0 * S;

  float acc[4][4] = {};
  for (int ic = 0; ic < 4; ++ic) {
    __syncthreads();
    for (int j = tid; j < KH * COLS * 32; j += 256) {
      const int col = j % COLS;
      const int row = (j / COLS) % KH;
      const int b = j / (COLS * KH);
      xs[(row * COLS + col) * BSTR + b] =
          x[(((size_t)b * 16 + icg * 4 + ic) * IH + in_row0 + row) * IH +
            in_col0 + col];
    }
    __syncthreads();
    const float* wic = wbase + ic * KHW;
    const float* xb = &xs[ow_off * S * BSTR + bg * 4];
    #pragma unroll
    for (int kc = 0; kc < KHW / 4; ++kc) {
      float wfa[4][4];
      #pragma unroll
      for (int o = 0; o < 4; ++o) {
        const float4 wf = *(const float4*)&wic[(size_t)o * (16 * KHW) + kc * 4];
        wfa[o][0] = wf.x; wfa[o][1] = wf.y; wfa[o][2] = wf.z; wfa[o][3] = wf.w;
      }
      #pragma unroll
      for (int kk = 0; kk < 4; ++kk) {
        const int k = kc * 4 + kk;
        const int kh = k / KH, kw = k % KH;
        const float4 xv = *(const float4*)&xb[(kh * COLS + kw) * BSTR];
        #pragma unroll
        for (int o = 0; o < 4; ++o) {
          acc[o][0] += wfa[o][kk] * xv.x;
          acc[o][1] += wfa[o][kk] * xv.y;
          acc[o][2] += wfa[o][kk] * xv.z;
          acc[o][3] += wfa[o][kk] * xv.w;
        }
      }
    }
    {  // tail k = KHW-1 (KHW % 4 == 1 for 81/49/25)
      const int k = KHW - 1;
      const int kh = k / KH, kw = k % KH;
      const float4 xv = *(const float4*)&xb[(kh * COLS + kw) * BSTR];
      #pragma unroll
      for (int o = 0; o < 4; ++o) {
        const float wt2 = wic[(size_t)o * (16 * KHW) + k];
        acc[o][0] += wt2 * xv.x;
        acc[o][1] += wt2 * xv.y;
        acc[o][2] += wt2 * xv.z;
        acc[o][3] += wt2 * xv.w;
      }
    }
  }

  float* pp = part + (size_t)icg * (32 * 16 * NPOS);
  #pragma unroll
  for (int o = 0; o < 4; ++o) {
    const int oc = og * 4 + o;
    #pragma unroll
    for (int i = 0; i < 4; ++i) {
      const int b = bg * 4 + i;
      pp[(((size_t)b * 16 + oc) * OH + oh) * OH + myow] = acc[o][i];
    }
  }
}

// combine 4 ic-partials + bias + relu. total = 32*16*npos.
__global__ __launch_bounds__(256) void lc_combine(const float* __restrict__ part,
                                                  const float* __restrict__ bias,
                                                  float* __restrict__ out,
                                                  int npos, int total) {
  const int i = blockIdx.x * 256 + threadIdx.x;
  if (i >= total) return;
  const int pos = i % npos;
  const int oc = (i / npos) & 15;
  const float v = part[i] + part[i + total] + part[i + 2 * total] +
                  part[i + 3 * total] + bias[oc * npos + pos];
  out[i] = fmaxf(v, 0.f);
}

// ---------------- fc1: transpose + reg-tiled GEMM
__global__ __launch_bounds__(256) void transpose_x(const float* __restrict__ h,
                                                   float* __restrict__ xt) {
  __shared__ float t[32][33];
  const int k0 = blockIdx.x * 32;
  const int lk = threadIdx.x & 31, lb = threadIdx.x >> 5;
  for (int bb = lb; bb < 32; bb += 8) {
    const int k = k0 + lk;
    t[bb][lk] = (k < 7056) ? h[(size_t)bb * 7056 + k] : 0.f;
  }
  __syncthreads();
  for (int kk = lb; kk < 32; kk += 8) {
    const int k = k0 + kk;
    if (k < 7056) xt[(size_t)k * 32 + lk] = t[lk][kk];
  }
}

__global__ __launch_bounds__(256) void fc1_v2(const float* __restrict__ xt,
                                              const float* __restrict__ w,
                                              const float* __restrict__ bias,
                                              float* __restrict__ out) {
  const int lane = threadIdx.x & 63;
  const int b0 = (threadIdx.x >> 6) * 8;
  const int n0 = blockIdx.x * 8;
  float acc[8][8] = {};
  for (int it = 0; it < 28; ++it) {
    const int kb = it * 256 + lane * 4;
    float4 wf[8], xa[4], xb[4];
    if (kb < 7056) {
      #pragma unroll
      for (int n = 0; n < 8; ++n)
        wf[n] = *(const float4*)&w[(size_t)(n0 + n) * 7056 + kb];
      #pragma unroll
      for (int j = 0; j < 4; ++j) {
        xa[j] = *(const float4*)&xt[(size_t)(kb + j) * 32 + b0];
        xb[j] = *(const float4*)&xt[(size_t)(kb + j) * 32 + b0 + 4];
      }
    } else {
      #pragma unroll
      for (int n = 0; n < 8; ++n) wf[n] = make_float4(0.f, 0.f, 0.f, 0.f);
      #pragma unroll
      for (int j = 0; j < 4; ++j) {
        xa[j] = make_float4(0.f, 0.f, 0.f, 0.f);
        xb[j] = make_float4(0.f, 0.f, 0.f, 0.f);
      }
    }
    #pragma unroll
    for (int n = 0; n < 8; ++n) {
      const float wk[4] = {wf[n].x, wf[n].y, wf[n].z, wf[n].w};
      #pragma unroll
      for (int j = 0; j < 4; ++j) {
        acc[n][0] += wk[j] * xa[j].x;
        acc[n][1] += wk[j] * xa[j].y;
        acc[n][2] += wk[j] * xa[j].z;
        acc[n][3] += wk[j] * xa[j].w;
        acc[n][4] += wk[j] * xb[j].x;
        acc[n][5] += wk[j] * xb[j].y;
        acc[n][6] += wk[j] * xb[j].z;
        acc[n][7] += wk[j] * xb[j].w;
      }
    }
  }
  #pragma unroll
  for (int n = 0; n < 8; ++n)
    #pragma unroll
    for (int c = 0; c < 8; ++c)
      #pragma unroll
      for (int m = 1; m < 64; m <<= 1)
        acc[n][c] += __shfl_xor(acc[n][c], m, 64);
  float val = 0.f;
  #pragma unroll
  for (int n = 0; n < 8; ++n)
    #pragma unroll
    for (int c = 0; c < 8; ++c)
      if (lane == n * 8 + c) val = acc[n][c];
  const int n_l = lane >> 3, b_l = lane & 7;
  out[(size_t)(b0 + b_l) * 4096 + n0 + n_l] = val + bias[n0 + n_l];
}

extern "C" void kernel_launch(void* const* d_in, const int* in_sizes, int n_in,
                              void* d_out, int out_size, void* d_ws, size_t ws_size,
                              hipStream_t stream) {
  const float* x       = (const float*)d_in[0];
  const float* conv1_w = (const float*)d_in[1];
  const float* conv1_b = (const float*)d_in[2];
  const float* conv2_w = (const float*)d_in[3];
  const float* conv2_b = (const float*)d_in[4];
  const float* lc1_w   = (const float*)d_in[5];
  const float* lc1_b   = (const float*)d_in[6];
  const float* lc2_w   = (const float*)d_in[7];
  const float* lc2_b   = (const float*)d_in[8];
  const float* lc3_w   = (const float*)d_in[9];
  const float* lc3_b   = (const float*)d_in[10];
  const float* fc1_w   = (const float*)d_in[11];
  const float* fc1_b   = (const float*)d_in[12];
  float* out = (float*)d_out;
  char* ws = (char*)d_ws;

  float* h1  = (float*)(ws + 0);           // 32*32*142*142      82,591,744 B
  float* p1  = (float*)(ws + 82591744);    // 32*32*71*71        20,647,936 B
  float* h2  = (float*)(ws + 103239680);   // 32*16*63*63         8,128,512 B
  float* h3  = (float*)(ws + 0);           // 32*16*55*55         6,195,200 B
  float* h4  = (float*)(ws + 8388608);     // 32*16*25*25         1,280,000 B
  float* h5  = (float*)(ws + 16777216);    // 32*16*21*21           903,168 B
  float* xt  = (float*)(ws + 33554432);    // 7056*32               903,168 B
  float* c2p = (float*)(ws + 41943040);    // 4*32*16*63*63      32,514,048 B (dead after conv2_combine)
  float* lcp = (float*)(ws + 41943040);    // 4*32*16*55*55 max  24,780,800 B (reused per lc layer)

  conv1_v3<<<dim3(5, 9, 32), 256, 0, stream>>>(x, conv1_w, conv1_b, h1);
  pool_3_2_1<<<20164, 256, 0, stream>>>(h1, p1);
  conv2_part<<<dim3(2, 4, 128), 128, 0, stream>>>(p1, conv2_w, c2p);
  conv2_combine<<<7938, 256, 0, stream>>>(c2p, conv2_b, h2);

  lc_v5<9, 1, 63, 55><<<dim3(7 * 55, 4), 256, 0, stream>>>(h2, lc1_w, lcp);
  lc_combine<<<(32 * 16 * 3025 + 255) / 256, 256, 0, stream>>>(
      lcp, lc1_b, h3, 3025, 32 * 16 * 3025);
  lc_v5<7, 2, 55, 25><<<dim3(4 * 25, 4), 256, 0, stream>>>(h3, lc2_w, lcp);
  lc_combine<<<(32 * 16 * 625 + 255) / 256, 256, 0, stream>>>(
      lcp, lc2_b, h4, 625, 32 * 16 * 625);
  lc_v5<5, 1, 25, 21><<<dim3(3 * 21, 4), 256, 0, stream>>>(h4, lc3_w, lcp);
  lc_combine<<<(32 * 16 * 441 + 255) / 256, 256, 0, stream>>>(
      lcp, lc3_b, h5, 441, 32 * 16 * 441);

  transpose_x<<<221, 256, 0, stream>>>(h5, xt);
  fc1_v2<<<512, 256, 0, stream>>>(xt, fc1_w, fc1_b, out);
}